// Round 1
// baseline (44.828 us; speedup 1.0000x reference)
//
#include <hip/hip_runtime.h>

// CrossCompressUnit on MI355X.
// Per row b (B=16384, D=1024):
//   s1 = e[b]·w_vv, s2 = v[b]·w_ev, s3 = e[b]·w_ve, s4 = v[b]·w_ee
//   v_out[b,i] = v[b,i]*s1 + e[b,i]*s2 + bias_v[i]
//   e_out[b,i] = v[b,i]*s3 + e[b,i]*s4 + bias_e[i]
// One 256-thread block per row; each thread owns 4 consecutive floats
// (float4 load/store), so v/e are read exactly once. Memory-bound:
// 256 MiB total traffic -> ~41 us at 6.3 TB/s.

#define CCU_BATCH 16384
#define CCU_DIM   1024

__global__ __launch_bounds__(256) void ccu_kernel(
    const float* __restrict__ v,  const float* __restrict__ e,
    const float* __restrict__ wvv, const float* __restrict__ wev,
    const float* __restrict__ wve, const float* __restrict__ wee,
    const float* __restrict__ bias_v, const float* __restrict__ bias_e,
    float* __restrict__ vout, float* __restrict__ eout)
{
    const int b  = blockIdx.x;
    const int t  = threadIdx.x;
    const int i4 = t * 4;                       // first float index owned by this thread
    const size_t row = (size_t)b * CCU_DIM;

    const float4 vv = *reinterpret_cast<const float4*>(v + row + i4);
    const float4 ee = *reinterpret_cast<const float4*>(e + row + i4);
    const float4 w1 = *reinterpret_cast<const float4*>(wvv + i4);
    const float4 w2 = *reinterpret_cast<const float4*>(wev + i4);
    const float4 w3 = *reinterpret_cast<const float4*>(wve + i4);
    const float4 w4 = *reinterpret_cast<const float4*>(wee + i4);

    // partial dots
    float s1 = ee.x*w1.x + ee.y*w1.y + ee.z*w1.z + ee.w*w1.w;  // e · w_vv
    float s2 = vv.x*w2.x + vv.y*w2.y + vv.z*w2.z + vv.w*w2.w;  // v · w_ev
    float s3 = ee.x*w3.x + ee.y*w3.y + ee.z*w3.z + ee.w*w3.w;  // e · w_ve
    float s4 = vv.x*w4.x + vv.y*w4.y + vv.z*w4.z + vv.w*w4.w;  // v · w_ee

    // wave (64-lane) butterfly reduce
    #pragma unroll
    for (int off = 32; off > 0; off >>= 1) {
        s1 += __shfl_down(s1, off, 64);
        s2 += __shfl_down(s2, off, 64);
        s3 += __shfl_down(s3, off, 64);
        s4 += __shfl_down(s4, off, 64);
    }

    // cross-wave reduce via LDS (4 waves x 4 sums)
    __shared__ float red[4][4];
    const int wave = t >> 6;
    const int lane = t & 63;
    if (lane == 0) {
        red[wave][0] = s1; red[wave][1] = s2;
        red[wave][2] = s3; red[wave][3] = s4;
    }
    __syncthreads();
    s1 = red[0][0] + red[1][0] + red[2][0] + red[3][0];
    s2 = red[0][1] + red[1][1] + red[2][1] + red[3][1];
    s3 = red[0][2] + red[1][2] + red[2][2] + red[3][2];
    s4 = red[0][3] + red[1][3] + red[2][3] + red[3][3];

    const float4 bv = *reinterpret_cast<const float4*>(bias_v + i4);
    const float4 be = *reinterpret_cast<const float4*>(bias_e + i4);

    float4 o1, o2;
    o1.x = vv.x*s1 + ee.x*s2 + bv.x;
    o1.y = vv.y*s1 + ee.y*s2 + bv.y;
    o1.z = vv.z*s1 + ee.z*s2 + bv.z;
    o1.w = vv.w*s1 + ee.w*s2 + bv.w;
    o2.x = vv.x*s3 + ee.x*s4 + be.x;
    o2.y = vv.y*s3 + ee.y*s4 + be.y;
    o2.z = vv.z*s3 + ee.z*s4 + be.z;
    o2.w = vv.w*s3 + ee.w*s4 + be.w;

    *reinterpret_cast<float4*>(vout + row + i4) = o1;
    *reinterpret_cast<float4*>(eout + row + i4) = o2;
}

extern "C" void kernel_launch(void* const* d_in, const int* in_sizes, int n_in,
                              void* d_out, int out_size, void* d_ws, size_t ws_size,
                              hipStream_t stream) {
    const float* v      = (const float*)d_in[0];
    const float* e      = (const float*)d_in[1];
    const float* wvv    = (const float*)d_in[2];
    const float* wev    = (const float*)d_in[3];
    const float* wve    = (const float*)d_in[4];
    const float* wee    = (const float*)d_in[5];
    const float* bias_v = (const float*)d_in[6];
    const float* bias_e = (const float*)d_in[7];

    float* vout = (float*)d_out;                                   // [B, D]
    float* eout = vout + (size_t)CCU_BATCH * CCU_DIM;              // [B, D]

    ccu_kernel<<<CCU_BATCH, 256, 0, stream>>>(
        v, e, wvv, wev, wve, wee, bias_v, bias_e, vout, eout);
}

// Round 2
// 43.403 us; speedup vs baseline: 1.0328x; 1.0328x over previous
//
#include <hip/hip_runtime.h>

// CrossCompressUnit on MI355X — wave-per-row variant.
// Per row b (B=16384, D=1024):
//   s1 = e[b]·w_vv, s2 = v[b]·w_ev, s3 = e[b]·w_ve, s4 = v[b]·w_ee
//   v_out[b,i] = v[b,i]*s1 + e[b,i]*s2 + bias_v[i]
//   e_out[b,i] = v[b,i]*s3 + e[b,i]*s4 + bias_e[i]
//
// One 64-lane wave per row: each lane owns 4 float4 chunks at stride 256
// (fully coalesced 1 KiB/instr), reduction is a wave-local __shfl_xor
// butterfly (no __syncthreads, no LDS). 4 waves/block, 4096 blocks.
// Outputs use non-temporal stores so the 134 MB of input can stay
// L3-resident across graph replays.

#define CCU_BATCH 16384
#define CCU_DIM   1024

typedef float f32x4 __attribute__((ext_vector_type(4)));

__global__ __launch_bounds__(256) void ccu_kernel(
    const float* __restrict__ v,  const float* __restrict__ e,
    const float* __restrict__ wvv, const float* __restrict__ wev,
    const float* __restrict__ wve, const float* __restrict__ wee,
    const float* __restrict__ bias_v, const float* __restrict__ bias_e,
    float* __restrict__ vout, float* __restrict__ eout)
{
    const int t    = threadIdx.x;
    const int wave = t >> 6;
    const int lane = t & 63;
    const int b    = blockIdx.x * 4 + wave;     // one row per wave
    const size_t row = (size_t)b * CCU_DIM;

    f32x4 vv[4], ee[4];
    float s1 = 0.f, s2 = 0.f, s3 = 0.f, s4 = 0.f;

    #pragma unroll
    for (int k = 0; k < 4; ++k) {
        const int idx = k * 256 + lane * 4;     // coalesced: lane i -> bytes i*16
        vv[k] = *reinterpret_cast<const f32x4*>(v + row + idx);
        ee[k] = *reinterpret_cast<const f32x4*>(e + row + idx);
        const f32x4 w1 = *reinterpret_cast<const f32x4*>(wvv + idx);
        const f32x4 w2 = *reinterpret_cast<const f32x4*>(wev + idx);
        const f32x4 w3 = *reinterpret_cast<const f32x4*>(wve + idx);
        const f32x4 w4 = *reinterpret_cast<const f32x4*>(wee + idx);
        s1 += ee[k].x*w1.x + ee[k].y*w1.y + ee[k].z*w1.z + ee[k].w*w1.w;
        s2 += vv[k].x*w2.x + vv[k].y*w2.y + vv[k].z*w2.z + vv[k].w*w2.w;
        s3 += ee[k].x*w3.x + ee[k].y*w3.y + ee[k].z*w3.z + ee[k].w*w3.w;
        s4 += vv[k].x*w4.x + vv[k].y*w4.y + vv[k].z*w4.z + vv[k].w*w4.w;
    }

    // wave-local butterfly reduce; all 64 lanes end with the full sums
    #pragma unroll
    for (int off = 32; off > 0; off >>= 1) {
        s1 += __shfl_xor(s1, off, 64);
        s2 += __shfl_xor(s2, off, 64);
        s3 += __shfl_xor(s3, off, 64);
        s4 += __shfl_xor(s4, off, 64);
    }

    #pragma unroll
    for (int k = 0; k < 4; ++k) {
        const int idx = k * 256 + lane * 4;
        const f32x4 bv = *reinterpret_cast<const f32x4*>(bias_v + idx);
        const f32x4 be = *reinterpret_cast<const f32x4*>(bias_e + idx);
        f32x4 o1, o2;
        o1.x = vv[k].x*s1 + ee[k].x*s2 + bv.x;
        o1.y = vv[k].y*s1 + ee[k].y*s2 + bv.y;
        o1.z = vv[k].z*s1 + ee[k].z*s2 + bv.z;
        o1.w = vv[k].w*s1 + ee[k].w*s2 + bv.w;
        o2.x = vv[k].x*s3 + ee[k].x*s4 + be.x;
        o2.y = vv[k].y*s3 + ee[k].y*s4 + be.y;
        o2.z = vv[k].z*s3 + ee[k].z*s4 + be.z;
        o2.w = vv[k].w*s3 + ee[k].w*s4 + be.w;
        __builtin_nontemporal_store(o1, reinterpret_cast<f32x4*>(vout + row + idx));
        __builtin_nontemporal_store(o2, reinterpret_cast<f32x4*>(eout + row + idx));
    }
}

extern "C" void kernel_launch(void* const* d_in, const int* in_sizes, int n_in,
                              void* d_out, int out_size, void* d_ws, size_t ws_size,
                              hipStream_t stream) {
    const float* v      = (const float*)d_in[0];
    const float* e      = (const float*)d_in[1];
    const float* wvv    = (const float*)d_in[2];
    const float* wev    = (const float*)d_in[3];
    const float* wve    = (const float*)d_in[4];
    const float* wee    = (const float*)d_in[5];
    const float* bias_v = (const float*)d_in[6];
    const float* bias_e = (const float*)d_in[7];

    float* vout = (float*)d_out;                                   // [B, D]
    float* eout = vout + (size_t)CCU_BATCH * CCU_DIM;              // [B, D]

    ccu_kernel<<<CCU_BATCH / 4, 256, 0, stream>>>(
        v, e, wvv, wev, wve, wee, bias_v, bias_e, vout, eout);
}